// Round 6
// baseline (325.589 us; speedup 1.0000x reference)
//
#include <hip/hip_runtime.h>
#include <math.h>

// Problem constants
#define BB    64
#define TT    512
#define TWOH  1024
#define WPB   4                  // waves per block; 1 t-row per wave
#define TCB   WPB                // 4 rows per block-chunk
#define NCHUNK (TT / TCB)        // 128 chunk-partials per b
#define NP_STRIDE ((TT + 1) * TWOH)  // 513*1024

// native clang vector type (vectorized loads/stores)
typedef float vfloat4 __attribute__((ext_vector_type(4)));

// NOTE (R3 post-mortem): __builtin_nontemporal_store on out_np caused
// post-timing divergence under the harness's re-poison path — no nt stores.
// NOTE (R1-R4): fused read+compute+big-write pins at ~2.7 TB/s across 6
// structural variants; write-only fills run 6.8 TB/s on the same chip.
// NOTE (R5): splitting into 3 full passes over prev regressed (+59 us) —
// the copy's write stream evicts prev from L3 between kernels. prev must
// be read at most twice.
// THIS ROUND: compute pass is READ-ONLY (scores+ct partials, 34 MB writes,
// the ~5 TB/s kernel class); the new_prev copy is delegated to the system
// blit via ONE hipMemcpy2DAsync (dpitch 513 rows, spitch 512 rows), issued
// right after the compute pass so it reads prev L3-warm.
// Falsifier: if the blit dispatch also shows ~2.7 TB/s, mixed r+w is
// globally capped -> revert to R2 fused (82 us single pass) = roofline.

// direct global->LDS DMA, 16B per lane; lds dst is WAVE-UNIFORM base
// (HW adds lane*16), global src is per-lane.
__device__ __forceinline__ void gload_lds16(const float* g, float* l) {
    __builtin_amdgcn_global_load_lds(
        (const __attribute__((address_space(1))) unsigned int*)g,
        (__attribute__((address_space(3))) unsigned int*)l,
        16, 0, 0);
}

// -------------------------------------------------------------------------
// K1: q[b][e] = sum_d h[b,d] * W[d,e]  (full-K, single kernel)
// grid = (4 e-chunks, 64 b) = 256 blocks, 256 threads.
// W reads are coalesced per d-step; 64 b-blocks reuse W via L2/L3.
// -------------------------------------------------------------------------
__global__ __launch_bounds__(256) void k_qgemm(const float* __restrict__ h,
                                               const float* __restrict__ W,
                                               float* __restrict__ q) {
    const int tid = threadIdx.x;
    const int e   = blockIdx.x * 256 + tid;      // 0..1023
    const int b   = blockIdx.y;                  // 0..63

    __shared__ float sh[TWOH];
    ((vfloat4*)sh)[tid] = ((const vfloat4*)(h + (size_t)b * TWOH))[tid];
    __syncthreads();

    const float* __restrict__ Wp = W + e;
    float acc = 0.f;
    #pragma unroll 16
    for (int d = 0; d < TWOH; ++d)
        acc = fmaf(sh[d], Wp[(size_t)d * TWOH], acc);

    q[(size_t)b * TWOH + e] = acc;
}

// -------------------------------------------------------------------------
// K2: READ-ONLY compute pass (no big writes). Each wave owns ONE t-row:
//   4x global_load_lds (row -> wave-private 4KB LDS) | 4x q float4 loads
//   -> vmcnt(0) (wave-local) -> ds_read row: dot partials -> butterfly ->
//   score to LDS -> ONE barrier -> block softmax over 4 scores ->
//   weighted combine of 4 LDS rows -> one 4-row partial (M,L,o) per block.
// LDS 16.4 KB, VGPR ~48 -> __launch_bounds__(256,8): 8 blocks/CU,
// 32 waves/CU. grid = (NCHUNK=128, 64 b) = 8192 blocks.
// -------------------------------------------------------------------------
__global__ __launch_bounds__(256, 8) void k_scores_ct(const float* __restrict__ prev,
                                                      const float* __restrict__ q,
                                                      float* __restrict__ ws_m,
                                                      float* __restrict__ ws_l,
                                                      float* __restrict__ ws_ct) {
    const int tid  = threadIdx.x;
    const int lane = tid & 63;
    const int wid  = tid >> 6;
    const int c    = blockIdx.x;                 // chunk 0..127
    const int b    = blockIdx.y;                 // 0..63
    const int t    = c * TCB + wid;              // this wave's row

    __shared__ float srow[WPB][TWOH];            // 16 KB, wave-private rows
    __shared__ float sscore[WPB];

    // 1) DMA this wave's row into its LDS region (no VGPR destinations)
    const float* gbase = prev + ((size_t)b * TT + t) * TWOH;
    #pragma unroll
    for (int j = 0; j < 4; ++j)
        gload_lds16(gbase + j * 256 + lane * 4, &srow[wid][j * 256]);

    // 2) q[b] lane-slice (L2-hot)
    const vfloat4* __restrict__ qv = (const vfloat4*)(q + (size_t)b * TWOH);
    const vfloat4 q0 = qv[lane];
    const vfloat4 q1 = qv[64 + lane];
    const vfloat4 q2 = qv[128 + lane];
    const vfloat4 q3 = qv[192 + lane];

    // DMA completion tracked by this wave's vmcnt only; no barrier needed.
    asm volatile("s_waitcnt vmcnt(0)" ::: "memory");
    __builtin_amdgcn_sched_barrier(0);

    // 3) dot partials from LDS
    const vfloat4* sr = (const vfloat4*)&srow[wid][0];
    const vfloat4 v0 = sr[lane];
    const vfloat4 v1 = sr[64 + lane];
    const vfloat4 v2 = sr[128 + lane];
    const vfloat4 v3 = sr[192 + lane];
    float d0 = v0.x * q0.x; d0 = fmaf(v0.y, q0.y, d0);
    d0 = fmaf(v0.z, q0.z, d0); d0 = fmaf(v0.w, q0.w, d0);
    float d1 = v1.x * q1.x; d1 = fmaf(v1.y, q1.y, d1);
    d1 = fmaf(v1.z, q1.z, d1); d1 = fmaf(v1.w, q1.w, d1);
    float d2 = v2.x * q2.x; d2 = fmaf(v2.y, q2.y, d2);
    d2 = fmaf(v2.z, q2.z, d2); d2 = fmaf(v2.w, q2.w, d2);
    float d3 = v3.x * q3.x; d3 = fmaf(v3.y, q3.y, d3);
    d3 = fmaf(v3.z, q3.z, d3); d3 = fmaf(v3.w, q3.w, d3);
    float pd = (d0 + d1) + (d2 + d3);
    #pragma unroll
    for (int off = 32; off > 0; off >>= 1)
        pd += __shfl_xor(pd, off, 64);
    if (lane == 0) sscore[wid] = pd;
    __syncthreads();

    // 4) block softmax over the 4 wave-uniform scores
    const float s0 = sscore[0], s1 = sscore[1], s2 = sscore[2], s3 = sscore[3];
    const float M  = fmaxf(fmaxf(s0, s1), fmaxf(s2, s3));
    const float a0 = __expf(s0 - M);
    const float a1 = __expf(s1 - M);
    const float a2 = __expf(s2 - M);
    const float a3 = __expf(s3 - M);
    const float L  = (a0 + a1) + (a2 + a3);

    // 5) weighted combine of the 4 rows; thread tid owns float4 index tid
    const vfloat4 x0 = ((const vfloat4*)&srow[0][0])[tid];
    const vfloat4 x1 = ((const vfloat4*)&srow[1][0])[tid];
    const vfloat4 x2 = ((const vfloat4*)&srow[2][0])[tid];
    const vfloat4 x3 = ((const vfloat4*)&srow[3][0])[tid];
    vfloat4 o;
    o.x = fmaf(a3, x3.x, fmaf(a2, x2.x, fmaf(a1, x1.x, a0 * x0.x)));
    o.y = fmaf(a3, x3.y, fmaf(a2, x2.y, fmaf(a1, x1.y, a0 * x0.y)));
    o.z = fmaf(a3, x3.z, fmaf(a2, x2.z, fmaf(a1, x1.z, a0 * x0.z)));
    o.w = fmaf(a3, x3.w, fmaf(a2, x2.w, fmaf(a1, x1.w, a0 * x0.w)));
    ((vfloat4*)(ws_ct + ((size_t)b * NCHUNK + c) * TWOH))[tid] = o;
    if (tid == 0) {
        ws_m[b * NCHUNK + c] = M;
        ws_l[b * NCHUNK + c] = L;
    }
}

// -------------------------------------------------------------------------
// K3: combine NCHUNK=128 chunk partials per b; also new_prev[b,512,:] = h[b,:].
// grid = (4 e-chunks, 64 b) = 256 blocks; thread owns one e.
// -------------------------------------------------------------------------
__global__ __launch_bounds__(256) void k_finalize(const float* __restrict__ h,
                                                  const float* __restrict__ ws_m,
                                                  const float* __restrict__ ws_l,
                                                  const float* __restrict__ ws_ct,
                                                  float* __restrict__ out_ct,
                                                  float* __restrict__ out_np) {
    const int tid = threadIdx.x;
    const int e   = blockIdx.x * 256 + tid;
    const int b   = blockIdx.y;

    const float* __restrict__ wm = ws_m + b * NCHUNK;
    const float* __restrict__ wl = ws_l + b * NCHUNK;

    float M = -INFINITY;
    #pragma unroll 32
    for (int i = 0; i < NCHUNK; ++i) M = fmaxf(M, wm[i]);

    const float* __restrict__ cp = ws_ct + (size_t)b * NCHUNK * TWOH + e;
    float L = 0.f;
    float acc = 0.f;
    #pragma unroll 32
    for (int i = 0; i < NCHUNK; ++i) {
        const float ce = __expf(wm[i] - M);
        L   = fmaf(ce, wl[i], L);
        acc = fmaf(ce, cp[(size_t)i * TWOH], acc);
    }
    out_ct[b * TWOH + e] = acc * (1.0f / L);

    // concat row: new_prev[b, T, :] = h[b, :]
    out_np[(size_t)b * NP_STRIDE + (size_t)TT * TWOH + e] = h[b * TWOH + e];
}

extern "C" void kernel_launch(void* const* d_in, const int* in_sizes, int n_in,
                              void* d_out, int out_size, void* d_ws, size_t ws_size,
                              hipStream_t stream) {
    const float* h    = (const float*)d_in[0];   // (64, 1024)
    const float* prev = (const float*)d_in[1];   // (64, 512, 1024)
    const float* W    = (const float*)d_in[2];   // (1, 1024, 1024)
    float* out    = (float*)d_out;
    float* out_ct = out;                         // (64, 1024)
    float* out_np = out + BB * TWOH;             // (64, 513, 1024)

    // ws layout (floats): q[64*1024] | m[64*128] | l[64*128] | ct[64*128*1024]
    // total ~= 34 MB.
    float* q   = (float*)d_ws;
    float* wsm = q + BB * TWOH;
    float* wsl = wsm + BB * NCHUNK;
    float* wsc = wsl + BB * NCHUNK;

    k_qgemm    <<<dim3(4, BB),      256, 0, stream>>>(h, W, q);
    k_scores_ct<<<dim3(NCHUNK, BB), 256, 0, stream>>>(prev, q, wsm, wsl, wsc);

    // new_prev[b, 0:512, :] = prev[b, :, :] via the system blit:
    // 64 rows of 2 MB, dst pitch 513*4KB, src pitch 512*4KB.
    hipMemcpy2DAsync(out_np, (size_t)NP_STRIDE * sizeof(float),
                     prev,   (size_t)TT * TWOH * sizeof(float),
                     (size_t)TT * TWOH * sizeof(float), BB,
                     hipMemcpyDeviceToDevice, stream);

    k_finalize <<<dim3(4, BB),      256, 0, stream>>>(h, wsm, wsl, wsc, out_ct, out_np);
}

// Round 7
// 290.020 us; speedup vs baseline: 1.1226x; 1.1226x over previous
//
#include <hip/hip_runtime.h>
#include <math.h>

// Problem constants
#define BB    64
#define TT    512
#define TWOH  1024
#define RPW   4                  // t-rows per WAVE (straight-line, no loop-carry)
#define WPB   4                  // waves per block (256 threads)
#define TC    (RPW * WPB)        // 16 rows per block-chunk
#define NCHUNK (TT / TC)         // 32 chunk-partials per b
#define NP_STRIDE ((TT + 1) * TWOH)  // 513*1024

// native clang vector type (vectorized loads/stores)
typedef float vfloat4 __attribute__((ext_vector_type(4)));

// NOTE (R3 post-mortem): __builtin_nontemporal_store on out_np caused
// post-timing divergence under the harness's re-poison path — no nt stores.
// NOTE (R1-R6 synthesis): the fused single-pass kernel pins at ~2.7 TB/s
// HBM-visible (~3.3 TB/s effective incl. L3-absorbed fetch) across FIVE
// structural variants (register phases, rotating prefetch, straight-line,
// LDS-DMA x2 occupancies). Splitting the pass (R5 pure kernels: +59 us;
// R6 system blit: +63 us) regresses — extra passes over prev/new_prev cost
// more than the fused cap loses. This file is the measured champion (R2
// structure, 262.1 us) with one cleanup: full-K qgemm writes q directly
// (drops the 4-way qpart re-read in the hot kernel).
// Floor arithmetic: 82 us fused pass + ~166 us harness re-poison fills
// (untouchable, in timed region) + ~15 us small kernels ~= 262 us.

// -------------------------------------------------------------------------
// K1: q[b][e] = sum_d h[b,d] * W[d,e]  (full-K, single kernel)
// grid = (4 e-chunks, 64 b) = 256 blocks, 256 threads.
// W reads are coalesced per d-step; 64 b-blocks reuse W via L2/L3.
// -------------------------------------------------------------------------
__global__ __launch_bounds__(256) void k_qgemm(const float* __restrict__ h,
                                               const float* __restrict__ W,
                                               float* __restrict__ q) {
    const int tid = threadIdx.x;
    const int e   = blockIdx.x * 256 + tid;      // 0..1023
    const int b   = blockIdx.y;                  // 0..63

    __shared__ float sh[TWOH];
    ((vfloat4*)sh)[tid] = ((const vfloat4*)(h + (size_t)b * TWOH))[tid];
    __syncthreads();

    const float* __restrict__ Wp = W + e;
    float acc = 0.f;
    #pragma unroll 16
    for (int d = 0; d < TWOH; ++d)
        acc = fmaf(sh[d], Wp[(size_t)d * TWOH], acc);

    q[(size_t)b * TWOH + e] = acc;
}

// -------------------------------------------------------------------------
// K2: each wave owns RPW=4 consecutive t-rows, fully straight-lined:
//   16 float4 loads (MLP=16) -> 16 copy-stores -> 4 wave dots (butterfly)
//   -> chunk-local softmax over the 4 wave-uniform scores (no branch)
//   -> ct accumulate in registers -> 4-wave LDS combine (one barrier)
//   -> one 16-row partial (m,l,ct) per block.
// grid = (NCHUNK=32, 64 b) = 2048 blocks.
// -------------------------------------------------------------------------
__global__ __launch_bounds__(256, 4) void k_scores_ct(const float* __restrict__ prev,
                                                      const float* __restrict__ q,
                                                      float* __restrict__ out_np,
                                                      float* __restrict__ ws_m,
                                                      float* __restrict__ ws_l,
                                                      float* __restrict__ ws_ct) {
    const int tid  = threadIdx.x;
    const int lane = tid & 63;
    const int wid  = tid >> 6;
    const int c    = blockIdx.x;                 // chunk 0..31
    const int b    = blockIdx.y;                 // 0..63
    const int t0   = c * TC + wid * RPW;         // this wave's first row

    __shared__ float s_ct[WPB][TWOH];
    __shared__ float s_m[WPB];
    __shared__ float s_l[WPB];

    // q[b] lane-slice (pre-reduced, L2-hot)
    const vfloat4* __restrict__ qv = (const vfloat4*)(q + (size_t)b * TWOH);
    vfloat4 qf[4];
    #pragma unroll
    for (int j = 0; j < 4; ++j)
        qf[j] = qv[j * 64 + lane];

    const vfloat4* __restrict__ prow =
        (const vfloat4*)(prev + ((size_t)b * TT + (size_t)t0) * TWOH) + lane;
    vfloat4* __restrict__ nprow =
        (vfloat4*)(out_np + (size_t)b * NP_STRIDE + (size_t)t0 * TWOH) + lane;

    // all 16 row-loads issued back-to-back
    vfloat4 cv[RPW][4];
    #pragma unroll
    for (int r = 0; r < RPW; ++r)
        #pragma unroll
        for (int j = 0; j < 4; ++j)
            cv[r][j] = prow[r * 256 + j * 64];

    // fused concat-copy (first consumer; compiler drains vmcnt progressively)
    #pragma unroll
    for (int r = 0; r < RPW; ++r)
        #pragma unroll
        for (int j = 0; j < 4; ++j)
            nprow[r * 256 + j * 64] = cv[r][j];

    // wave-local dots: 4 independent chains per row, then combine
    float pd[RPW];
    #pragma unroll
    for (int r = 0; r < RPW; ++r) {
        float d0 = cv[r][0].x * qf[0].x;
        d0 = fmaf(cv[r][0].y, qf[0].y, d0);
        d0 = fmaf(cv[r][0].z, qf[0].z, d0);
        d0 = fmaf(cv[r][0].w, qf[0].w, d0);
        float d1 = cv[r][1].x * qf[1].x;
        d1 = fmaf(cv[r][1].y, qf[1].y, d1);
        d1 = fmaf(cv[r][1].z, qf[1].z, d1);
        d1 = fmaf(cv[r][1].w, qf[1].w, d1);
        float d2 = cv[r][2].x * qf[2].x;
        d2 = fmaf(cv[r][2].y, qf[2].y, d2);
        d2 = fmaf(cv[r][2].z, qf[2].z, d2);
        d2 = fmaf(cv[r][2].w, qf[2].w, d2);
        float d3 = cv[r][3].x * qf[3].x;
        d3 = fmaf(cv[r][3].y, qf[3].y, d3);
        d3 = fmaf(cv[r][3].z, qf[3].z, d3);
        d3 = fmaf(cv[r][3].w, qf[3].w, d3);
        pd[r] = (d0 + d1) + (d2 + d3);
    }
    #pragma unroll
    for (int r = 0; r < RPW; ++r)
        #pragma unroll
        for (int off = 32; off > 0; off >>= 1)
            pd[r] += __shfl_xor(pd[r], off, 64);

    // chunk-local softmax over 4 wave-uniform scores: no branch, no rescale
    const float m = fmaxf(fmaxf(pd[0], pd[1]), fmaxf(pd[2], pd[3]));
    float a[RPW];
    float l = 0.f;
    #pragma unroll
    for (int r = 0; r < RPW; ++r) {
        a[r] = __expf(pd[r] - m);
        l += a[r];
    }
    vfloat4 ct[4];
    #pragma unroll
    for (int j = 0; j < 4; ++j) ct[j] = (vfloat4)(0.f);
    #pragma unroll
    for (int r = 0; r < RPW; ++r)
        #pragma unroll
        for (int j = 0; j < 4; ++j) {
            ct[j].x = fmaf(a[r], cv[r][j].x, ct[j].x);
            ct[j].y = fmaf(a[r], cv[r][j].y, ct[j].y);
            ct[j].z = fmaf(a[r], cv[r][j].z, ct[j].z);
            ct[j].w = fmaf(a[r], cv[r][j].w, ct[j].w);
        }

    // 4-wave combine via LDS (single barrier, at the very end)
    vfloat4* __restrict__ sct = (vfloat4*)&s_ct[wid][0];
    #pragma unroll
    for (int j = 0; j < 4; ++j) sct[j * 64 + lane] = ct[j];
    if (lane == 0) { s_m[wid] = m; s_l[wid] = l; }
    __syncthreads();

    const float M = fmaxf(fmaxf(s_m[0], s_m[1]), fmaxf(s_m[2], s_m[3]));
    float L = 0.f;
    float co[WPB];
    #pragma unroll
    for (int w = 0; w < WPB; ++w) {
        co[w] = __expf(s_m[w] - M);
        L = fmaf(co[w], s_l[w], L);
    }
    vfloat4 o = (vfloat4)(0.f);
    #pragma unroll
    for (int w = 0; w < WPB; ++w) {
        const vfloat4 v = ((const vfloat4*)&s_ct[w][0])[tid];
        o.x = fmaf(co[w], v.x, o.x);
        o.y = fmaf(co[w], v.y, o.y);
        o.z = fmaf(co[w], v.z, o.z);
        o.w = fmaf(co[w], v.w, o.w);
    }
    ((vfloat4*)(ws_ct + ((size_t)b * NCHUNK + c) * TWOH))[tid] = o;
    if (tid == 0) {
        ws_m[b * NCHUNK + c] = M;
        ws_l[b * NCHUNK + c] = L;
    }
}

// -------------------------------------------------------------------------
// K3: combine NCHUNK=32 chunk partials per b; also new_prev[b,512,:] = h[b,:].
// Single fused loop: coef computed once, feeds both L and the ct accumulate.
// grid = (4 e-chunks, 64 b) = 256 blocks; thread owns one e.
// -------------------------------------------------------------------------
__global__ __launch_bounds__(256) void k_finalize(const float* __restrict__ h,
                                                  const float* __restrict__ ws_m,
                                                  const float* __restrict__ ws_l,
                                                  const float* __restrict__ ws_ct,
                                                  float* __restrict__ out_ct,
                                                  float* __restrict__ out_np) {
    const int tid = threadIdx.x;
    const int e   = blockIdx.x * 256 + tid;
    const int b   = blockIdx.y;

    const float* __restrict__ wm = ws_m + b * NCHUNK;
    const float* __restrict__ wl = ws_l + b * NCHUNK;

    float M = -INFINITY;
    #pragma unroll
    for (int i = 0; i < NCHUNK; ++i) M = fmaxf(M, wm[i]);

    const float* __restrict__ cp = ws_ct + (size_t)b * NCHUNK * TWOH + e;
    float L = 0.f;
    float acc = 0.f;
    #pragma unroll
    for (int i = 0; i < NCHUNK; ++i) {
        const float ce = __expf(wm[i] - M);
        L   = fmaf(ce, wl[i], L);
        acc = fmaf(ce, cp[(size_t)i * TWOH], acc);
    }
    out_ct[b * TWOH + e] = acc * (1.0f / L);

    // concat row: new_prev[b, T, :] = h[b, :]
    out_np[(size_t)b * NP_STRIDE + (size_t)TT * TWOH + e] = h[b * TWOH + e];
}

extern "C" void kernel_launch(void* const* d_in, const int* in_sizes, int n_in,
                              void* d_out, int out_size, void* d_ws, size_t ws_size,
                              hipStream_t stream) {
    const float* h    = (const float*)d_in[0];   // (64, 1024)
    const float* prev = (const float*)d_in[1];   // (64, 512, 1024)
    const float* W    = (const float*)d_in[2];   // (1, 1024, 1024)
    float* out    = (float*)d_out;
    float* out_ct = out;                         // (64, 1024)
    float* out_np = out + BB * TWOH;             // (64, 513, 1024)

    // ws layout (floats): q[64*1024] | m[64*32] | l[64*32] | ct[64*32*1024]
    // total ~= 8.7 MB.
    float* q   = (float*)d_ws;
    float* wsm = q + BB * TWOH;
    float* wsl = wsm + BB * NCHUNK;
    float* wsc = wsl + BB * NCHUNK;

    k_qgemm    <<<dim3(4, BB),      256, 0, stream>>>(h, W, q);
    k_scores_ct<<<dim3(NCHUNK, BB), 256, 0, stream>>>(prev, q, out_np, wsm, wsl, wsc);
    k_finalize <<<dim3(4, BB),      256, 0, stream>>>(h, wsm, wsl, wsc, out_ct, out_np);
}

// Round 8
// 285.984 us; speedup vs baseline: 1.1385x; 1.0141x over previous
//
#include <hip/hip_runtime.h>
#include <math.h>

// Problem constants
#define BB    64
#define TT    512
#define TWOH  1024
#define WPB   4                  // waves per block (256 threads); 1 t-row per wave
#define TCB   WPB                // 4 rows per block-chunk
#define NCHUNK (TT / TCB)        // 128 chunk-partials per b
#define NP_STRIDE ((TT + 1) * TWOH)  // 513*1024

// native clang vector type (vectorized loads/stores)
typedef float vfloat4 __attribute__((ext_vector_type(4)));

// NOTE (R3 post-mortem): __builtin_nontemporal_store on out_np caused
// post-timing divergence under the harness's re-poison path — no nt stores.
// NOTE (R1-R7 synthesis): fused single-pass r+w pins at ~2.6 TB/s HBM at
// bounds(256,4) across 5 structures; ONLY R4's occupancy-doubled DMA
// variant (bounds(256,8), 1 row/wave) went below 80.8 us. R5/R6 splits
// regressed (+59/+63). Harness noise band is +-15 us (R7: identical config
// to the 262.1 champion measured 290.0; fills vary 78-87 us each).
// THIS ROUND: R4 hot kernel + full-K qgemm (no qreduce) + ILP-tuned
// 128-partial finalize. Pre-commitment: total >= 262 => ROOFLINE
// (floor = 166 us fills + ~75-82 us capped pass + ~15 us small + noise).

// direct global->LDS DMA, 16B per lane; lds dst is WAVE-UNIFORM base
// (HW adds lane*16), global src is per-lane.
__device__ __forceinline__ void gload_lds16(const float* g, float* l) {
    __builtin_amdgcn_global_load_lds(
        (const __attribute__((address_space(1))) unsigned int*)g,
        (__attribute__((address_space(3))) unsigned int*)l,
        16, 0, 0);
}

// -------------------------------------------------------------------------
// K1: q[b][e] = sum_d h[b,d] * W[d,e]  (full-K). 4 independent acc chains
// cut the serial-FMA dep latency 4x. grid = (4 e-chunks, 64 b), 256 thr.
// W reads coalesced per d-step; 64 b-blocks reuse W via L2.
// -------------------------------------------------------------------------
__global__ __launch_bounds__(256) void k_qgemm(const float* __restrict__ h,
                                               const float* __restrict__ W,
                                               float* __restrict__ q) {
    const int tid = threadIdx.x;
    const int e   = blockIdx.x * 256 + tid;      // 0..1023
    const int b   = blockIdx.y;                  // 0..63

    __shared__ float sh[TWOH];
    ((vfloat4*)sh)[tid] = ((const vfloat4*)(h + (size_t)b * TWOH))[tid];
    __syncthreads();

    const float* __restrict__ Wp = W + e;
    float a0 = 0.f, a1 = 0.f, a2 = 0.f, a3 = 0.f;
    #pragma unroll 8
    for (int d = 0; d < TWOH; d += 4) {
        a0 = fmaf(sh[d],     Wp[(size_t)(d)     * TWOH], a0);
        a1 = fmaf(sh[d + 1], Wp[(size_t)(d + 1) * TWOH], a1);
        a2 = fmaf(sh[d + 2], Wp[(size_t)(d + 2) * TWOH], a2);
        a3 = fmaf(sh[d + 3], Wp[(size_t)(d + 3) * TWOH], a3);
    }
    q[(size_t)b * TWOH + e] = (a0 + a1) + (a2 + a3);
}

// -------------------------------------------------------------------------
// K2: occupancy-first (the only structure measured <80.8 us). Each wave
// owns ONE t-row: 4x global_load_lds (row -> wave-private 4KB LDS) | 4x q
// float4 loads -> vmcnt(0) (wave-local, no barrier) -> ds_read row:
// copy-store to out_np + dot partials -> butterfly -> score to LDS -> ONE
// barrier -> block softmax over 4 scores -> weighted combine of 4 LDS rows
// -> one 4-row partial (M,L,o) per block.
// LDS 16.4 KB, VGPR ~48 -> bounds(256,8): 8 blocks/CU, 32 waves/CU.
// grid = (NCHUNK=128, 64 b) = 8192 blocks.
// -------------------------------------------------------------------------
__global__ __launch_bounds__(256, 8) void k_scores_ct(const float* __restrict__ prev,
                                                      const float* __restrict__ q,
                                                      float* __restrict__ out_np,
                                                      float* __restrict__ ws_m,
                                                      float* __restrict__ ws_l,
                                                      float* __restrict__ ws_ct) {
    const int tid  = threadIdx.x;
    const int lane = tid & 63;
    const int wid  = tid >> 6;
    const int c    = blockIdx.x;                 // chunk 0..127
    const int b    = blockIdx.y;                 // 0..63
    const int t    = c * TCB + wid;              // this wave's row

    __shared__ float srow[WPB][TWOH];            // 16 KB, wave-private rows
    __shared__ float sscore[WPB];

    // 1) DMA this wave's row into its LDS region (no VGPR destinations)
    const float* gbase = prev + ((size_t)b * TT + t) * TWOH;
    #pragma unroll
    for (int j = 0; j < 4; ++j)
        gload_lds16(gbase + j * 256 + lane * 4, &srow[wid][j * 256]);

    // 2) q[b] lane-slice (L2-hot), in flight together with the DMA
    const vfloat4* __restrict__ qv = (const vfloat4*)(q + (size_t)b * TWOH);
    const vfloat4 q0 = qv[lane];
    const vfloat4 q1 = qv[64 + lane];
    const vfloat4 q2 = qv[128 + lane];
    const vfloat4 q3 = qv[192 + lane];

    // DMA completion tracked by this wave's vmcnt only; no barrier needed.
    asm volatile("s_waitcnt vmcnt(0)" ::: "memory");
    __builtin_amdgcn_sched_barrier(0);

    // 3) copy-store + dot partials from LDS
    const vfloat4* sr = (const vfloat4*)&srow[wid][0];
    vfloat4* __restrict__ nprow =
        (vfloat4*)(out_np + (size_t)b * NP_STRIDE + (size_t)t * TWOH) + lane;
    const vfloat4 v0 = sr[lane];
    const vfloat4 v1 = sr[64 + lane];
    const vfloat4 v2 = sr[128 + lane];
    const vfloat4 v3 = sr[192 + lane];
    nprow[0]   = v0;
    nprow[64]  = v1;
    nprow[128] = v2;
    nprow[192] = v3;
    float d0 = v0.x * q0.x; d0 = fmaf(v0.y, q0.y, d0);
    d0 = fmaf(v0.z, q0.z, d0); d0 = fmaf(v0.w, q0.w, d0);
    float d1 = v1.x * q1.x; d1 = fmaf(v1.y, q1.y, d1);
    d1 = fmaf(v1.z, q1.z, d1); d1 = fmaf(v1.w, q1.w, d1);
    float d2 = v2.x * q2.x; d2 = fmaf(v2.y, q2.y, d2);
    d2 = fmaf(v2.z, q2.z, d2); d2 = fmaf(v2.w, q2.w, d2);
    float d3 = v3.x * q3.x; d3 = fmaf(v3.y, q3.y, d3);
    d3 = fmaf(v3.z, q3.z, d3); d3 = fmaf(v3.w, q3.w, d3);
    float pd = (d0 + d1) + (d2 + d3);
    #pragma unroll
    for (int off = 32; off > 0; off >>= 1)
        pd += __shfl_xor(pd, off, 64);
    if (lane == 0) sscore[wid] = pd;
    __syncthreads();

    // 4) block softmax over the 4 wave-uniform scores
    const float s0 = sscore[0], s1 = sscore[1], s2 = sscore[2], s3 = sscore[3];
    const float M  = fmaxf(fmaxf(s0, s1), fmaxf(s2, s3));
    const float a0 = __expf(s0 - M);
    const float a1 = __expf(s1 - M);
    const float a2 = __expf(s2 - M);
    const float a3 = __expf(s3 - M);
    const float L  = (a0 + a1) + (a2 + a3);

    // 5) weighted combine of the 4 rows; thread tid owns float4 index tid
    const vfloat4 x0 = ((const vfloat4*)&srow[0][0])[tid];
    const vfloat4 x1 = ((const vfloat4*)&srow[1][0])[tid];
    const vfloat4 x2 = ((const vfloat4*)&srow[2][0])[tid];
    const vfloat4 x3 = ((const vfloat4*)&srow[3][0])[tid];
    vfloat4 o;
    o.x = fmaf(a3, x3.x, fmaf(a2, x2.x, fmaf(a1, x1.x, a0 * x0.x)));
    o.y = fmaf(a3, x3.y, fmaf(a2, x2.y, fmaf(a1, x1.y, a0 * x0.y)));
    o.z = fmaf(a3, x3.z, fmaf(a2, x2.z, fmaf(a1, x1.z, a0 * x0.z)));
    o.w = fmaf(a3, x3.w, fmaf(a2, x2.w, fmaf(a1, x1.w, a0 * x0.w)));
    ((vfloat4*)(ws_ct + ((size_t)b * NCHUNK + c) * TWOH))[tid] = o;
    if (tid == 0) {
        ws_m[b * NCHUNK + c] = M;
        ws_l[b * NCHUNK + c] = L;
    }
}

// -------------------------------------------------------------------------
// K3: combine NCHUNK=128 chunk partials per b (33.5 MB stream) with 4
// independent accumulator chains; also new_prev[b,512,:] = h[b,:].
// grid = (4 e-chunks, 64 b) = 256 blocks; thread owns one e.
// Per chunk-iter a wave reads 256 consecutive bytes — coalesced stream.
// -------------------------------------------------------------------------
__global__ __launch_bounds__(256) void k_finalize(const float* __restrict__ h,
                                                  const float* __restrict__ ws_m,
                                                  const float* __restrict__ ws_l,
                                                  const float* __restrict__ ws_ct,
                                                  float* __restrict__ out_ct,
                                                  float* __restrict__ out_np) {
    const int tid = threadIdx.x;
    const int e   = blockIdx.x * 256 + tid;
    const int b   = blockIdx.y;

    const float* __restrict__ wm = ws_m + b * NCHUNK;
    const float* __restrict__ wl = ws_l + b * NCHUNK;

    float M = -INFINITY;
    #pragma unroll 32
    for (int i = 0; i < NCHUNK; ++i) M = fmaxf(M, wm[i]);

    const float* __restrict__ cp = ws_ct + (size_t)b * NCHUNK * TWOH + e;
    float L0 = 0.f, L1 = 0.f, L2 = 0.f, L3 = 0.f;
    float c0 = 0.f, c1 = 0.f, c2 = 0.f, c3 = 0.f;
    #pragma unroll 8
    for (int i = 0; i < NCHUNK; i += 4) {
        const float e0 = __expf(wm[i]     - M);
        const float e1 = __expf(wm[i + 1] - M);
        const float e2 = __expf(wm[i + 2] - M);
        const float e3 = __expf(wm[i + 3] - M);
        L0 = fmaf(e0, wl[i],     L0);
        L1 = fmaf(e1, wl[i + 1], L1);
        L2 = fmaf(e2, wl[i + 2], L2);
        L3 = fmaf(e3, wl[i + 3], L3);
        c0 = fmaf(e0, cp[(size_t)(i)     * TWOH], c0);
        c1 = fmaf(e1, cp[(size_t)(i + 1) * TWOH], c1);
        c2 = fmaf(e2, cp[(size_t)(i + 2) * TWOH], c2);
        c3 = fmaf(e3, cp[(size_t)(i + 3) * TWOH], c3);
    }
    const float L   = (L0 + L1) + (L2 + L3);
    const float acc = (c0 + c1) + (c2 + c3);
    out_ct[b * TWOH + e] = acc * (1.0f / L);

    // concat row: new_prev[b, T, :] = h[b, :]
    out_np[(size_t)b * NP_STRIDE + (size_t)TT * TWOH + e] = h[b * TWOH + e];
}

extern "C" void kernel_launch(void* const* d_in, const int* in_sizes, int n_in,
                              void* d_out, int out_size, void* d_ws, size_t ws_size,
                              hipStream_t stream) {
    const float* h    = (const float*)d_in[0];   // (64, 1024)
    const float* prev = (const float*)d_in[1];   // (64, 512, 1024)
    const float* W    = (const float*)d_in[2];   // (1, 1024, 1024)
    float* out    = (float*)d_out;
    float* out_ct = out;                         // (64, 1024)
    float* out_np = out + BB * TWOH;             // (64, 513, 1024)

    // ws layout (floats): q[64*1024] | m[64*128] | l[64*128] | ct[64*128*1024]
    // total ~= 34 MB.
    float* q   = (float*)d_ws;
    float* wsm = q + BB * TWOH;
    float* wsl = wsm + BB * NCHUNK;
    float* wsc = wsl + BB * NCHUNK;

    k_qgemm    <<<dim3(4, BB),      256, 0, stream>>>(h, W, q);
    k_scores_ct<<<dim3(NCHUNK, BB), 256, 0, stream>>>(prev, q, out_np, wsm, wsl, wsc);
    k_finalize <<<dim3(4, BB),      256, 0, stream>>>(h, wsm, wsl, wsc, out_ct, out_np);
}